// Round 10
// baseline (207.111 us; speedup 1.0000x reference)
//
#include <hip/hip_runtime.h>
#include <hip/hip_bf16.h>

// NVFP4 dynamic linear: x[2,2048,4096] f32, w[4096,4096] f32, bias[4096] -> out f32
// M=4096, N=4096, K=4096.
//
// amax -> fused coalesced quant/dequant to bf16 (exact: e2m1 x e4m3 fits
// bf16; fp32 MFMA accumulate exact) -> 256x128-tile bf16 MFMA GEMM at
// TWO blocks/CU (ring-3 LDS 72 KiB). Cross-block overlap hides the
// barrier/vmcnt drains that capped the 1-block/CU 256x256 variant at 43%.
//
// ws: [0,8) amax bits | [256, +32MB) dx bf16 | [+32MB) dw bf16

typedef unsigned short u16;
typedef __bf16 bf16x8 __attribute__((ext_vector_type(8)));
typedef float f32x4 __attribute__((ext_vector_type(4)));

#define GLD_LDS(gsrc, ldst)                                                     \
  __builtin_amdgcn_global_load_lds(                                             \
      (const __attribute__((address_space(1))) void*)(gsrc),                    \
      (__attribute__((address_space(3))) void*)(ldst), 16, 0, 0)

#define SBAR()                                                                  \
  do {                                                                          \
    asm volatile("" ::: "memory");                                              \
    __builtin_amdgcn_s_barrier();                                               \
    asm volatile("" ::: "memory");                                              \
  } while (0)

// ---------------- rounding helpers (bit-exact vs numpy RTNE) -----------------

__device__ __forceinline__ float round_e4m3(float v) {
  if (v < 0.015625f) {                        // subnormal grid, step 2^-9
    return rintf(v * 512.0f) * 0.001953125f;
  }
  unsigned b = __float_as_uint(v);
  unsigned e = (b >> 23) & 0xFFu;
  float step = __uint_as_float((e - 3u) << 23); // 2^(e-127-3)
  return rintf(v / step) * step;
}

__device__ __forceinline__ float round_e2m1(float v) {
  float a = fabsf(v);
  float step = (a < 2.0f) ? 0.5f : ((a < 4.0f) ? 1.0f : 2.0f);
  float q = fminf(rintf(a / step) * step, 6.0f);
  return copysignf(q, v);
}

// ---------------- kernel 1: global amax of |x| and |w| ----------------------

__global__ void nvfp4_amax_kernel(const float* __restrict__ x,
                                  const float* __restrict__ w,
                                  unsigned* __restrict__ sc, int nx4, int nw4) {
  const float4* src = blockIdx.y ? (const float4*)w : (const float4*)x;
  int n4 = blockIdx.y ? nw4 : nx4;
  float m = 0.f;
  for (int i = blockIdx.x * blockDim.x + threadIdx.x; i < n4;
       i += gridDim.x * blockDim.x) {
    float4 v = src[i];
    m = fmaxf(m, fmaxf(fmaxf(fabsf(v.x), fabsf(v.y)),
                       fmaxf(fabsf(v.z), fabsf(v.w))));
  }
#pragma unroll
  for (int off = 32; off; off >>= 1) m = fmaxf(m, __shfl_down(m, off));
  __shared__ float red[4];
  if ((threadIdx.x & 63) == 0) red[threadIdx.x >> 6] = m;
  __syncthreads();
  if (threadIdx.x == 0) {
    m = fmaxf(fmaxf(red[0], red[1]), fmaxf(red[2], red[3]));
    atomicMax(&sc[blockIdx.y], __float_as_uint(m));
  }
}

// ------------- kernel 2: fused coalesced quantize->dequantize ---------------

__global__ void nvfp4_quant_kernel(const float* __restrict__ x,
                                   const float* __restrict__ w,
                                   u16* __restrict__ dx, u16* __restrict__ dw,
                                   const unsigned* __restrict__ sc,
                                   int nx4, int nw4) {
  int g = blockIdx.x * blockDim.x + threadIdx.x;   // global float4 index
  const float* src; u16* dst; int which, i4;
  if (g < nx4) { src = x; dst = dx; which = 0; i4 = g; }
  else {
    i4 = g - nx4; if (i4 >= nw4) return;
    src = w; dst = dw; which = 1;
  }
  float4 v = ((const float4*)src)[i4];

  float m = fmaxf(fmaxf(fabsf(v.x), fabsf(v.y)), fmaxf(fabsf(v.z), fabsf(v.w)));
  m = fmaxf(m, __shfl_xor(m, 1));                  // 4-lane group = 16-elem block
  m = fmaxf(m, __shfl_xor(m, 2));

  float amax = fmaxf(__uint_as_float(sc[which]), 1e-12f);
  float gs = 2688.0f / amax;
  float sf = round_e4m3((m * gs) / 6.0f);
  float sfs = fmaxf(sf, 1e-12f);
  float r = gs / sfs;

  ushort4 o;
  o.x = (u16)(__float_as_uint(round_e2m1(v.x * r) * sf) >> 16);
  o.y = (u16)(__float_as_uint(round_e2m1(v.y * r) * sf) >> 16);
  o.z = (u16)(__float_as_uint(round_e2m1(v.z * r) * sf) >> 16);
  o.w = (u16)(__float_as_uint(round_e2m1(v.w * r) * sf) >> 16);
  ((ushort4*)dst)[i4] = o;                         // 8B coalesced
}

// ---------------- kernel 4: 256x128 bf16 GEMM, 2 blocks/CU ------------------
// 256 threads = 4 waves (2M x 2N), per-wave 128x64 = acc[8][4]. BK=32.
// Ring-3 LDS (72 KiB) -> 2 blocks/CU; cross-block overlap hides drains.
// Group = 2 K-tiles = 4 phases, stage t+2 (A then B), vmcnt(6) twice/group
// (6 = loads of the one newer tile allowed in flight).

#define BM 256
#define BN 128
#define BK 32

__global__ __launch_bounds__(256, 2) void nvfp4_gemm_kernel(
    const u16* __restrict__ A,   // dx [M][K]
    const u16* __restrict__ B,   // dw [N][K]
    const float* __restrict__ bias, const unsigned* __restrict__ sc,
    float* __restrict__ C, int M, int N, int K) {
  __shared__ u16 lA[3][BM * BK];   // 48 KiB
  __shared__ u16 lB[3][BN * BK];   // 24 KiB

  const int tid = threadIdx.x;
  const int lane = tid & 63;
  const int wv = tid >> 6;       // 0..3
  const int wm = wv >> 1;        // 0..1
  const int wn = wv & 1;         // 0..1

  // T1: XCD swizzle. 512 blocks; each XCD owns tile-rows {2x, 2x+1} x 32 cols.
  const int bid = blockIdx.x;
  const int xcd = bid & 7, loc = bid >> 3;         // loc 0..63
  const int tm0 = (xcd * 2 + (loc >> 5)) * BM;
  const int tn0 = (loc & 31) * BN;

  // ---- staging addressing (pre-swizzled global source, linear LDS dest) ----
  // chunk c covers rows 16c..16c+15; lane l -> row 16c+(l>>2), slot l&3.
  // swizzle key = (row>>1)&3 = (lane>>3)&3 (chunk-independent).
  const int r4 = lane >> 2;
  const int swz = ((lane & 3) ^ ((lane >> 3) & 3)) * 8;
  const u16* gAa[4]; const u16* gBb[2];
#pragma unroll
  for (int i = 0; i < 4; ++i)
    gAa[i] = A + (size_t)(tm0 + (i * 4 + wv) * 16 + r4) * K + swz;
#pragma unroll
  for (int i = 0; i < 2; ++i)
    gBb[i] = B + (size_t)(tn0 + (i * 4 + wv) * 16 + r4) * K + swz;
  const int ldw = wv * 512 + lane * 8;             // + i*2048 elems

#define STAGE_A(tt, bf)                                                         \
  do {                                                                          \
    _Pragma("unroll") for (int _i = 0; _i < 4; ++_i)                            \
        GLD_LDS(gAa[_i] + (size_t)(tt) * BK, &lA[bf][_i * 2048 + ldw]);         \
  } while (0)
#define STAGE_B(tt, bf)                                                         \
  do {                                                                          \
    _Pragma("unroll") for (int _i = 0; _i < 2; ++_i)                            \
        GLD_LDS(gBb[_i] + (size_t)(tt) * BK, &lB[bf][_i * 2048 + ldw]);         \
  } while (0)

  // ---- fragment addressing (T2 swizzle on read side, same involution) ------
  const int rb = lane & 15;
  const int cc = (((lane >> 4) ^ ((rb >> 1) & 3)) << 3);
  const int aoff = (wm * 128 + rb) * BK + cc;      // + i*512, ih: +2048
  const int boff = (wn * 64 + rb) * BK + cc;       // + j*512

  f32x4 acc[8][4] = {};
  const int NT = K / BK;                           // 128
  const int NG = NT / 2;                           // 64

  // prologue: stage tiles 0,1 (12 loads); vmcnt(6) -> tile 0 resident
  STAGE_A(0, 0); STAGE_B(0, 0);
  STAGE_A(1, 1); STAGE_B(1, 1);
  asm volatile("s_waitcnt vmcnt(6)" ::: "memory");
  SBAR();

  bf16x8 av[4], aw[4], bv[4];
  int cur = 0;                                     // buf of tile 2g

  for (int g = 0; g < NG; ++g) {
    int t1b = cur + 1; if (t1b == 3) t1b = 0;
    int s0b = t1b + 1; if (s0b == 3) s0b = 0;      // buf of tile 2g+2
    const int s0 = 2 * g + 2, s1 = 2 * g + 3;     // s1 -> buf cur
    const u16* bufA0 = lA[cur];
    const u16* bufB0 = lB[cur];
    const u16* bufA1 = lA[t1b];
    const u16* bufB1 = lB[t1b];
    const bool st = (g < NG - 1);

    // ---------------- P0: tile t0, rows 0-63 --------------------------------
#pragma unroll
    for (int j = 0; j < 4; ++j)
      bv[j] = *(const bf16x8*)(bufB0 + boff + j * 512);
#pragma unroll
    for (int i = 0; i < 4; ++i)
      av[i] = *(const bf16x8*)(bufA0 + aoff + i * 512);
    if (st) STAGE_A(s0, s0b);
    SBAR();
    __builtin_amdgcn_s_setprio(1);
#pragma unroll
    for (int i = 0; i < 4; ++i)
#pragma unroll
      for (int j = 0; j < 4; ++j)
        acc[i][j] = __builtin_amdgcn_mfma_f32_16x16x32_bf16(av[i], bv[j],
                                                            acc[i][j], 0, 0, 0);
    __builtin_amdgcn_s_setprio(0);
    SBAR();

    // ---------------- P1: tile t0, rows 64-127 ------------------------------
#pragma unroll
    for (int i = 0; i < 4; ++i)
      aw[i] = *(const bf16x8*)(bufA0 + aoff + 2048 + i * 512);
    if (st) STAGE_B(s0, s0b);
    SBAR();
    __builtin_amdgcn_s_setprio(1);
#pragma unroll
    for (int i = 0; i < 4; ++i)
#pragma unroll
      for (int j = 0; j < 4; ++j)
        acc[4 + i][j] = __builtin_amdgcn_mfma_f32_16x16x32_bf16(aw[i], bv[j],
                                                                acc[4 + i][j],
                                                                0, 0, 0);
    __builtin_amdgcn_s_setprio(0);
    if (st) asm volatile("s_waitcnt vmcnt(6)" ::: "memory");
    else    asm volatile("s_waitcnt vmcnt(0)" ::: "memory");
    SBAR();

    // ---------------- P2: tile t1, rows 0-63 --------------------------------
#pragma unroll
    for (int j = 0; j < 4; ++j)
      bv[j] = *(const bf16x8*)(bufB1 + boff + j * 512);
#pragma unroll
    for (int i = 0; i < 4; ++i)
      av[i] = *(const bf16x8*)(bufA1 + aoff + i * 512);
    if (st) STAGE_A(s1, cur);                      // s1 -> buf of old t0
    SBAR();
    __builtin_amdgcn_s_setprio(1);
#pragma unroll
    for (int i = 0; i < 4; ++i)
#pragma unroll
      for (int j = 0; j < 4; ++j)
        acc[i][j] = __builtin_amdgcn_mfma_f32_16x16x32_bf16(av[i], bv[j],
                                                            acc[i][j], 0, 0, 0);
    __builtin_amdgcn_s_setprio(0);
    SBAR();

    // ---------------- P3: tile t1, rows 64-127 ------------------------------
#pragma unroll
    for (int i = 0; i < 4; ++i)
      aw[i] = *(const bf16x8*)(bufA1 + aoff + 2048 + i * 512);
    if (st) STAGE_B(s1, cur);
    SBAR();
    __builtin_amdgcn_s_setprio(1);
#pragma unroll
    for (int i = 0; i < 4; ++i)
#pragma unroll
      for (int j = 0; j < 4; ++j)
        acc[4 + i][j] = __builtin_amdgcn_mfma_f32_16x16x32_bf16(aw[i], bv[j],
                                                                acc[4 + i][j],
                                                                0, 0, 0);
    __builtin_amdgcn_s_setprio(0);
    if (st) asm volatile("s_waitcnt vmcnt(6)" ::: "memory");
    SBAR();

    cur = s0b;                                     // buf of tile 2g+2
  }

  // ---------------- epilogue: out = alpha*acc + bias ------------------------
  float ax = fmaxf(__uint_as_float(sc[0]), 1e-12f);
  float aw_ = fmaxf(__uint_as_float(sc[1]), 1e-12f);
  float alpha = (ax * aw_) / 7225344.0f;           // amax_x*amax_w / 2688^2

  const int orow = (lane >> 4) * 4;                // C/D: col=lane&15, row=(lane>>4)*4+reg
  const int ocol = lane & 15;
#pragma unroll
  for (int ai = 0; ai < 8; ++ai) {
#pragma unroll
    for (int j = 0; j < 4; ++j) {
      int col = tn0 + wn * 64 + j * 16 + ocol;
      float bvv = bias[col];
#pragma unroll
      for (int rr = 0; rr < 4; ++rr) {
        int row = tm0 + wm * 128 + ai * 16 + orow + rr;
        C[(size_t)row * N + col] = alpha * acc[ai][j][rr] + bvv;
      }
    }
  }
#undef STAGE_A
#undef STAGE_B
}

// ---------------------------------------------------------------------------

extern "C" void kernel_launch(void* const* d_in, const int* in_sizes, int n_in,
                              void* d_out, int out_size, void* d_ws, size_t ws_size,
                              hipStream_t stream) {
  const float* x = (const float*)d_in[0];
  const float* w = (const float*)d_in[1];
  const float* bias = (const float*)d_in[2];
  float* out = (float*)d_out;

  const int N = in_sizes[2];
  const int K = in_sizes[1] / N;
  const int M = in_sizes[0] / K;

  unsigned char* ws = (unsigned char*)d_ws;
  unsigned* sc = (unsigned*)ws;
  u16* dx = (u16*)(ws + 256);
  u16* dw = (u16*)(ws + 256 + (size_t)M * K * sizeof(u16));

  hipMemsetAsync(sc, 0, 8, stream);

  const int nx4 = M * K / 4, nw4 = N * K / 4;
  nvfp4_amax_kernel<<<dim3(1024, 2), 256, 0, stream>>>(x, w, sc, nx4, nw4);

  nvfp4_quant_kernel<<<(nx4 + nw4 + 255) / 256, 256, 0, stream>>>(
      x, w, dx, dw, sc, nx4, nw4);

  nvfp4_gemm_kernel<<<dim3((M / BM) * (N / BN)), 256, 0, stream>>>(
      dx, dw, bias, sc, out, M, N, K);
}